// Round 4
// baseline (590.986 us; speedup 1.0000x reference)
//
#include <hip/hip_runtime.h>
#include <math.h>

#define NB 2
#define CDIM 512
#define NT 4096
#define LOG2E 1.44269504088896f
#define SHIFT 20.0f

typedef unsigned short u16;
typedef __attribute__((ext_vector_type(8))) short short8;
typedef __attribute__((ext_vector_type(4))) float f32x4;

union U8 { u16 v[8]; uint4 u4; };
union U4 { u16 v[4]; uint2 u2; };

__device__ __forceinline__ u16 f2bf(float f) {
    union { float f; unsigned u; } v; v.f = f;
    unsigned r = (v.u + 0x7fffu + ((v.u >> 16) & 1u)) >> 16;
    return (u16)r;
}
__device__ __forceinline__ float bf2f(u16 b) {
    union { float f; unsigned u; } v; v.u = ((unsigned)b) << 16; return v.f;
}
__device__ __forceinline__ float fexp2(float x) {
#if __has_builtin(__builtin_amdgcn_exp2f)
    return __builtin_amdgcn_exp2f(x);
#else
    return exp2f(x);
#endif
}
__device__ __forceinline__ float flog2(float x) {
#if __has_builtin(__builtin_amdgcn_logf)
    return __builtin_amdgcn_logf(x);
#else
    return log2f(x);
#endif
}

// ---------------- weight convert: W1=[Wb*log2e; Wc; alpha*Wd] bf16, W2f=beta*Wd bf16 ----------------
__global__ __launch_bounds__(256) void k_convW(
    const float* __restrict__ Wb, const float* __restrict__ Wc, const float* __restrict__ Wd,
    const float* __restrict__ alpha, const float* __restrict__ beta,
    u16* __restrict__ W1, u16* __restrict__ W2f)
{
    int r = blockIdx.x, t = threadIdx.x;
    const float* src; float scale; u16* dst;
    if (r < 640) {
        dst = W1 + (size_t)r * CDIM;
        if (r < 64)       { src = Wb + (size_t)r * CDIM;        scale = LOG2E; }
        else if (r < 128) { src = Wc + (size_t)(r - 64) * CDIM; scale = 1.f; }
        else              { src = Wd + (size_t)(r - 128) * CDIM; scale = alpha[0]; }
    } else {
        int rr = r - 640;
        dst = W2f + (size_t)rr * CDIM;
        src = Wd + (size_t)rr * CDIM;
        scale = beta[0];
    }
    float2 v = *(const float2*)&src[t * 2];
    unsigned p = (unsigned)f2bf(v.x * scale) | ((unsigned)f2bf(v.y * scale) << 16);
    *(unsigned*)&dst[t * 2] = p;
}

// ---------------- x [b][c][n] fp32 -> xT [b][n][c] bf16 (64x64 tiles via LDS) ----------------
__global__ __launch_bounds__(256) void k_prep(
    const float* __restrict__ x1, const float* __restrict__ x2,
    u16* __restrict__ x1T, u16* __restrict__ x2T)
{
    __shared__ float Lt[64][65];
    int t = threadIdx.x;
    int c0 = blockIdx.x * 64, n0 = blockIdx.y * 64;
    int which = blockIdx.z & 1, batch = blockIdx.z >> 1;
    const float* src = (which ? x2 : x1) + (size_t)batch * CDIM * NT;
    u16* dst = (which ? x2T : x1T) + (size_t)batch * NT * CDIM;
    #pragma unroll
    for (int p = 0; p < 4; p++) {
        int cr = p * 16 + (t >> 4), nc = (t & 15) * 4;
        float4 v = *(const float4*)&src[(size_t)(c0 + cr) * NT + n0 + nc];
        Lt[cr][nc] = v.x; Lt[cr][nc + 1] = v.y; Lt[cr][nc + 2] = v.z; Lt[cr][nc + 3] = v.w;
    }
    __syncthreads();
    #pragma unroll
    for (int p = 0; p < 2; p++) {
        int nr = p * 32 + (t >> 3), cc = (t & 7) * 8;
        U8 u;
        #pragma unroll
        for (int j = 0; j < 8; j++) u.v[j] = f2bf(Lt[cc + j][nr]);
        *(uint4*)&dst[(size_t)(n0 + nr) * CDIM + c0 + cc] = u.u4;
    }
}

// ---------------- projection GEMM (bf16 MFMA, K=512) ----------------
// oT==0: out yab[b][n][128] (a|b packed, bias applied).  oT 1..4: ft[b][c][m] (WHICH=1 raw, WHICH=2 +=, +bias)
template<int WHICH>
__global__ __launch_bounds__(256, 2) void k_gemm(
    const u16* __restrict__ W1, const u16* __restrict__ W2f,
    const u16* __restrict__ xT,
    const float* __restrict__ bb, const float* __restrict__ bc, const float* __restrict__ bd,
    const float* __restrict__ alpha, const float* __restrict__ beta,
    u16* __restrict__ yab, u16* __restrict__ ft)
{
    __shared__ u16 Wt[128][72];
    __shared__ u16 Xt[128][72];
    int t = threadIdx.x, lane = t & 63, w = t >> 6, q = lane >> 4, l15 = lane & 15;
    int nT_ = blockIdx.x, oT = blockIdx.y, batch = blockIdx.z;
    int n0 = nT_ * 128, o0 = oT * 128;
    const u16* Wsrc = (WHICH == 1 || oT == 0) ? (W1 + (size_t)o0 * CDIM)
                                              : (W2f + (size_t)(o0 - 128) * CDIM);
    const u16* xb = xT + ((size_t)batch * NT + n0) * CDIM;
    f32x4 acc[2][8];
    #pragma unroll
    for (int a = 0; a < 2; a++)
        #pragma unroll
        for (int b = 0; b < 8; b++) { f32x4 z = {0.f,0.f,0.f,0.f}; acc[a][b] = z; }

    for (int k0 = 0; k0 < CDIM; k0 += 64) {
        if (k0) __syncthreads();
        int r = t >> 1, h = t & 1;
        #pragma unroll
        for (int u = 0; u < 4; u++) {
            *(uint4*)&Wt[r][h * 32 + u * 8] = *(const uint4*)&Wsrc[(size_t)r * CDIM + k0 + h * 32 + u * 8];
            *(uint4*)&Xt[r][h * 32 + u * 8] = *(const uint4*)&xb[(size_t)r * CDIM + k0 + h * 32 + u * 8];
        }
        __syncthreads();
        if (oT == 0) {
            short8 af[2][2];
            #pragma unroll
            for (int ot = 0; ot < 2; ot++)
                #pragma unroll
                for (int kk = 0; kk < 2; kk++)
                    af[ot][kk] = *(const short8*)&Wt[w * 32 + ot * 16 + l15][kk * 32 + q * 8];
            #pragma unroll
            for (int kk = 0; kk < 2; kk++)
                #pragma unroll
                for (int i = 0; i < 8; i++) {
                    short8 bf = *(const short8*)&Xt[i * 16 + l15][kk * 32 + q * 8];
                    #pragma unroll
                    for (int ot = 0; ot < 2; ot++)
                        acc[ot][i] = __builtin_amdgcn_mfma_f32_16x16x32_bf16(af[ot][kk], bf, acc[ot][i], 0, 0, 0);
                }
        } else {
            short8 wf[2][2];
            #pragma unroll
            for (int ct = 0; ct < 2; ct++)
                #pragma unroll
                for (int kk = 0; kk < 2; kk++)
                    wf[ct][kk] = *(const short8*)&Wt[w * 32 + ct * 16 + l15][kk * 32 + q * 8];
            #pragma unroll
            for (int kk = 0; kk < 2; kk++)
                #pragma unroll
                for (int i = 0; i < 8; i++) {
                    short8 xf = *(const short8*)&Xt[i * 16 + l15][kk * 32 + q * 8];
                    #pragma unroll
                    for (int ct = 0; ct < 2; ct++)
                        acc[ct][i] = __builtin_amdgcn_mfma_f32_16x16x32_bf16(xf, wf[ct][kk], acc[ct][i], 0, 0, 0);
                }
        }
    }

    if (oT == 0) {
        #pragma unroll
        for (int ot = 0; ot < 2; ot++)
            #pragma unroll
            for (int i = 0; i < 8; i++) {
                int obase = w * 32 + ot * 16 + q * 4;
                int n = n0 + i * 16 + l15;
                U4 u;
                #pragma unroll
                for (int r = 0; r < 4; r++) {
                    int o = obase + r;
                    float bias = (o < 64) ? bb[o] * LOG2E : bc[o - 64];
                    u.v[r] = f2bf(acc[ot][i][r] + bias);
                }
                *(uint2*)&yab[((size_t)batch * NT + n) * 128 + obase] = u.u2;
            }
    } else {
        float bscale = (WHICH == 2) ? (alpha[0] + beta[0]) : 0.f;
        #pragma unroll
        for (int ct = 0; ct < 2; ct++)
            #pragma unroll
            for (int i = 0; i < 8; i++) {
                int c = (o0 - 128) + w * 32 + ct * 16 + l15;
                int mb = n0 + i * 16 + q * 4;
                u16* dst = &ft[((size_t)batch * CDIM + c) * NT + mb];
                U4 u;
                if (WHICH == 1) {
                    #pragma unroll
                    for (int r = 0; r < 4; r++) u.v[r] = f2bf(acc[ct][i][r]);
                } else {
                    U4 old; old.u2 = *(const uint2*)dst;
                    float bias = bd[c] * bscale;
                    #pragma unroll
                    for (int r = 0; r < 4; r++) u.v[r] = f2bf(acc[ct][i][r] + bf2f(old.v[r]) + bias);
                }
                *(uint2*)dst = u.u2;
            }
    }
}

// ---------------- denominators: denom[dir][b][n] = sum_m exp2(S - SHIFT) ----------------
// no LDS, no barriers: score operands straight from global (y rows are 16B-aligned)
__global__ __launch_bounds__(256, 4) void k_denom(
    const u16* __restrict__ yab1, const u16* __restrict__ yab2,
    float* __restrict__ denom)
{
    int t = threadIdx.x, lane = t & 63, w = t >> 6, q = lane >> 4, l15 = lane & 15;
    int x = blockIdx.x & 15;
    int batch = x & 1, m8 = x >> 1;            // m8 in 0..7, 512 m each
    int n0 = (blockIdx.x >> 4) * 32;
    const u16* y1 = yab1 + (size_t)batch * NT * 128;
    const u16* y2 = yab2 + (size_t)batch * NT * 128;

    short8 a1f[2][2], a2f[2][2];
    #pragma unroll
    for (int i = 0; i < 2; i++)
        #pragma unroll
        for (int kk = 0; kk < 2; kk++) {
            a1f[i][kk] = *(const short8*)&y1[(size_t)(n0 + i * 16 + l15) * 128 + kk * 32 + q * 8];
            a2f[i][kk] = *(const short8*)&y2[(size_t)(n0 + i * 16 + l15) * 128 + kk * 32 + q * 8];
        }

    float sm[2][2] = {{0.f,0.f},{0.f,0.f}};
    for (int mc = 0; mc < 512; mc += 64) {
        int mrow = m8 * 512 + mc + w * 16 + l15;
        const u16* r1 = y1 + (size_t)mrow * 128 + 64;
        const u16* r2 = y2 + (size_t)mrow * 128 + 64;
        short8 b1k0 = *(const short8*)(r1 + q * 8);
        short8 b1k1 = *(const short8*)(r1 + 32 + q * 8);
        short8 b2k0 = *(const short8*)(r2 + q * 8);
        short8 b2k1 = *(const short8*)(r2 + 32 + q * 8);
        #pragma unroll
        for (int i = 0; i < 2; i++) {
            f32x4 z = {0.f,0.f,0.f,0.f};
            f32x4 s12 = __builtin_amdgcn_mfma_f32_16x16x32_bf16(b2k0, a1f[i][0], z, 0, 0, 0);
            s12 = __builtin_amdgcn_mfma_f32_16x16x32_bf16(b2k1, a1f[i][1], s12, 0, 0, 0);
            f32x4 s21 = __builtin_amdgcn_mfma_f32_16x16x32_bf16(b1k0, a2f[i][0], z, 0, 0, 0);
            s21 = __builtin_amdgcn_mfma_f32_16x16x32_bf16(b1k1, a2f[i][1], s21, 0, 0, 0);
            #pragma unroll
            for (int r = 0; r < 4; r++) {
                sm[0][i] += fexp2(s12[r] - SHIFT);
                sm[1][i] += fexp2(s21[r] - SHIFT);
            }
        }
    }
    #pragma unroll
    for (int d = 0; d < 2; d++)
        #pragma unroll
        for (int i = 0; i < 2; i++) {
            float v = sm[d][i];
            v += __shfl_xor(v, 16);
            v += __shfl_xor(v, 32);
            if (q == 0)
                atomicAdd(&denom[((size_t)d * NB + batch) * NT + n0 + i * 16 + l15], v);
        }
}

// ---------------- P + apply: 16 query rows/block, m-split x2, atomic accumulate ----------------
// LDS = double-buffered P tile only (4.6 KB); one barrier per 64-m chunk.
__global__ __launch_bounds__(256, 4) void k_papply(
    const u16* __restrict__ yab1, const u16* __restrict__ yab2,
    const u16* __restrict__ ft, const float* __restrict__ denom,
    float* __restrict__ out)
{
    __shared__ u16 Pt[2][16][72];
    int t = threadIdx.x, lane = t & 63, w = t >> 6, q = lane >> 4, l15 = lane & 15;
    int x = blockIdx.x & 3;
    int batch = x & 1, mh = x >> 1;            // m-half: 2048 m each
    int n0 = (blockIdx.x >> 2) * 16;
    const u16* y1 = yab1 + (size_t)batch * NT * 128;
    const u16* y2 = yab2 + (size_t)batch * NT * 128;
    const u16* ftb = ft + (size_t)batch * CDIM * NT;

    // loop-invariant a-fragments (B operand: col=n, k=channel) straight from global
    short8 a1f[2], a2f[2];
    #pragma unroll
    for (int kk = 0; kk < 2; kk++) {
        a1f[kk] = *(const short8*)&y1[(size_t)(n0 + l15) * 128 + kk * 32 + q * 8];
        a2f[kk] = *(const short8*)&y2[(size_t)(n0 + l15) * 128 + kk * 32 + q * 8];
    }
    float ls12 = SHIFT + flog2(denom[(size_t)batch * NT + n0 + l15]);
    float ls21 = SHIFT + flog2(denom[((size_t)NB + batch) * NT + n0 + l15]);

    f32x4 o[8];
    #pragma unroll
    for (int j = 0; j < 8; j++) { f32x4 z = {0.f,0.f,0.f,0.f}; o[j] = z; }

    int pb = 0;
    for (int mc = 0; mc < 2048; mc += 64) {
        int mabs = mh * 2048 + mc;
        // ---- scores for this 64-m chunk (wave-private 16 m rows) ----
        int mrow = mabs + w * 16 + l15;
        const u16* r1 = y1 + (size_t)mrow * 128 + 64;
        const u16* r2 = y2 + (size_t)mrow * 128 + 64;
        short8 b1k0 = *(const short8*)(r1 + q * 8);
        short8 b1k1 = *(const short8*)(r1 + 32 + q * 8);
        short8 b2k0 = *(const short8*)(r2 + q * 8);
        short8 b2k1 = *(const short8*)(r2 + 32 + q * 8);
        f32x4 z = {0.f,0.f,0.f,0.f};
        f32x4 s12 = __builtin_amdgcn_mfma_f32_16x16x32_bf16(b2k0, a1f[0], z, 0, 0, 0);
        s12 = __builtin_amdgcn_mfma_f32_16x16x32_bf16(b2k1, a1f[1], s12, 0, 0, 0);
        f32x4 s21 = __builtin_amdgcn_mfma_f32_16x16x32_bf16(b1k0, a2f[0], z, 0, 0, 0);
        s21 = __builtin_amdgcn_mfma_f32_16x16x32_bf16(b1k1, a2f[1], s21, 0, 0, 0);
        U4 u;
        #pragma unroll
        for (int r = 0; r < 4; r++) {
            float p12 = fexp2(s12[r] - ls12);
            float p21 = fexp2(s21[r] - ls21);
            u.v[r] = f2bf(fabsf(p12 - p21));
        }
        *(uint2*)&Pt[pb][l15][w * 16 + q * 4] = u.u2;   // D: col=n(l15), rows=4 consecutive m
        __syncthreads();

        short8 pa0 = *(const short8*)&Pt[pb][l15][q * 8];
        short8 pa1 = *(const short8*)&Pt[pb][l15][32 + q * 8];

        // ---- apply: o[c-tile] += P @ ft^T, 1-deep ft prefetch pipeline ----
        const u16* fbase = ftb + mabs;
        short8 fc0, fc1;
        {
            const u16* fr = fbase + (size_t)(w * 128 + l15) * NT;
            fc0 = *(const short8*)(fr + q * 8);
            fc1 = *(const short8*)(fr + 32 + q * 8);
        }
        #pragma unroll
        for (int j = 0; j < 8; j++) {
            short8 fn0, fn1;
            if (j < 7) {
                const u16* fr = fbase + (size_t)(w * 128 + (j + 1) * 16 + l15) * NT;
                fn0 = *(const short8*)(fr + q * 8);
                fn1 = *(const short8*)(fr + 32 + q * 8);
            }
            o[j] = __builtin_amdgcn_mfma_f32_16x16x32_bf16(pa0, fc0, o[j], 0, 0, 0);
            o[j] = __builtin_amdgcn_mfma_f32_16x16x32_bf16(pa1, fc1, o[j], 0, 0, 0);
            if (j < 7) { fc0 = fn0; fc1 = fn1; }
        }
        pb ^= 1;
    }

    // epilogue: atomic accumulate into zero-initialized out
    #pragma unroll
    for (int j = 0; j < 8; j++) {
        int c = w * 128 + j * 16 + l15;
        float* dst = &out[((size_t)batch * CDIM + c) * NT + n0 + q * 4];
        #pragma unroll
        for (int r = 0; r < 4; r++)
            atomicAdd(dst + r, o[j][r]);
    }
}

extern "C" void kernel_launch(void* const* d_in, const int* in_sizes, int n_in,
                              void* d_out, int out_size, void* d_ws, size_t ws_size,
                              hipStream_t stream)
{
    const float* x1 = (const float*)d_in[0];
    const float* x2 = (const float*)d_in[1];
    const float* Wb = (const float*)d_in[2];
    const float* bb = (const float*)d_in[3];
    const float* Wc = (const float*)d_in[4];
    const float* bc = (const float*)d_in[5];
    const float* Wd = (const float*)d_in[6];
    const float* bd = (const float*)d_in[7];
    const float* alpha = (const float*)d_in[8];
    const float* beta  = (const float*)d_in[9];
    float* out = (float*)d_out;

    // ws layout (u16 units):
    u16* ws  = (u16*)d_ws;
    u16* x1T = ws;                      // [2][4096][512]  = 4,194,304
    u16* x2T = ws + 4194304;            //                 = 4,194,304
    u16* yab1 = ws + 8388608;           // [2][4096][128]  = 1,048,576
    u16* yab2 = ws + 9437184;           //                 = 1,048,576
    u16* ft   = ws + 10485760;          // [2][512][4096]  = 4,194,304
    u16* W1   = ws + 14680064;          // [640][512]      =   327,680
    u16* W2f  = ws + 15007744;          // [512][512]      =   262,144
    float* denom = (float*)(ws + 15269888);   // [2][2][4096] f32

    hipMemsetAsync(denom, 0, (size_t)2 * NB * NT * sizeof(float), stream);
    hipMemsetAsync(out, 0, (size_t)NB * CDIM * NT * sizeof(float), stream);
    k_convW<<<1152, 256, 0, stream>>>(Wb, Wc, Wd, alpha, beta, W1, W2f);
    k_prep<<<dim3(8, 64, 4), 256, 0, stream>>>(x1, x2, x1T, x2T);
    k_gemm<1><<<dim3(32, 5, 2), 256, 0, stream>>>(W1, W2f, x1T, bb, bc, bd, alpha, beta, yab1, ft);
    k_gemm<2><<<dim3(32, 5, 2), 256, 0, stream>>>(W1, W2f, x2T, bb, bc, bd, alpha, beta, yab2, ft);
    k_denom<<<2048, 256, 0, stream>>>(yab1, yab2, denom);
    k_papply<<<1024, 256, 0, stream>>>(yab1, yab2, ft, denom, out);
}

// Round 5
// 391.380 us; speedup vs baseline: 1.5100x; 1.5100x over previous
//
#include <hip/hip_runtime.h>
#include <math.h>

#define NB 2
#define CDIM 512
#define NT 4096
#define LOG2E 1.44269504088896f
#define SHIFT 20.0f

typedef unsigned short u16;
typedef __attribute__((ext_vector_type(8))) short short8;
typedef __attribute__((ext_vector_type(4))) float f32x4;

union U8 { u16 v[8]; uint4 u4; };
union U4 { u16 v[4]; uint2 u2; };

__device__ __forceinline__ u16 f2bf(float f) {
    union { float f; unsigned u; } v; v.f = f;
    unsigned r = (v.u + 0x7fffu + ((v.u >> 16) & 1u)) >> 16;
    return (u16)r;
}
__device__ __forceinline__ float bf2f(u16 b) {
    union { float f; unsigned u; } v; v.u = ((unsigned)b) << 16; return v.f;
}
__device__ __forceinline__ float fexp2(float x) {
#if __has_builtin(__builtin_amdgcn_exp2f)
    return __builtin_amdgcn_exp2f(x);
#else
    return exp2f(x);
#endif
}
__device__ __forceinline__ float flog2(float x) {
#if __has_builtin(__builtin_amdgcn_logf)
    return __builtin_amdgcn_logf(x);
#else
    return log2f(x);
#endif
}

// ---------------- weight convert: W1=[Wb*log2e; Wc; alpha*Wd] bf16, W2f=beta*Wd bf16 ----------------
__global__ __launch_bounds__(256) void k_convW(
    const float* __restrict__ Wb, const float* __restrict__ Wc, const float* __restrict__ Wd,
    const float* __restrict__ alpha, const float* __restrict__ beta,
    u16* __restrict__ W1, u16* __restrict__ W2f)
{
    int r = blockIdx.x, t = threadIdx.x;
    const float* src; float scale; u16* dst;
    if (r < 640) {
        dst = W1 + (size_t)r * CDIM;
        if (r < 64)       { src = Wb + (size_t)r * CDIM;        scale = LOG2E; }
        else if (r < 128) { src = Wc + (size_t)(r - 64) * CDIM; scale = 1.f; }
        else              { src = Wd + (size_t)(r - 128) * CDIM; scale = alpha[0]; }
    } else {
        int rr = r - 640;
        dst = W2f + (size_t)rr * CDIM;
        src = Wd + (size_t)rr * CDIM;
        scale = beta[0];
    }
    float2 v = *(const float2*)&src[t * 2];
    unsigned p = (unsigned)f2bf(v.x * scale) | ((unsigned)f2bf(v.y * scale) << 16);
    *(unsigned*)&dst[t * 2] = p;
}

// ---------------- x [b][c][n] fp32 -> xT [b][n][c] bf16 (64x64 tiles via LDS) ----------------
__global__ __launch_bounds__(256) void k_prep(
    const float* __restrict__ x1, const float* __restrict__ x2,
    u16* __restrict__ x1T, u16* __restrict__ x2T)
{
    __shared__ float Lt[64][65];
    int t = threadIdx.x;
    int c0 = blockIdx.x * 64, n0 = blockIdx.y * 64;
    int which = blockIdx.z & 1, batch = blockIdx.z >> 1;
    const float* src = (which ? x2 : x1) + (size_t)batch * CDIM * NT;
    u16* dst = (which ? x2T : x1T) + (size_t)batch * NT * CDIM;
    #pragma unroll
    for (int p = 0; p < 4; p++) {
        int cr = p * 16 + (t >> 4), nc = (t & 15) * 4;
        float4 v = *(const float4*)&src[(size_t)(c0 + cr) * NT + n0 + nc];
        Lt[cr][nc] = v.x; Lt[cr][nc + 1] = v.y; Lt[cr][nc + 2] = v.z; Lt[cr][nc + 3] = v.w;
    }
    __syncthreads();
    #pragma unroll
    for (int p = 0; p < 2; p++) {
        int nr = p * 32 + (t >> 3), cc = (t & 7) * 8;
        U8 u;
        #pragma unroll
        for (int j = 0; j < 8; j++) u.v[j] = f2bf(Lt[cc + j][nr]);
        *(uint4*)&dst[(size_t)(n0 + nr) * CDIM + c0 + cc] = u.u4;
    }
}

// ---------------- projection GEMM (bf16 MFMA, K=512) ----------------
template<int WHICH>
__global__ __launch_bounds__(256, 2) void k_gemm(
    const u16* __restrict__ W1, const u16* __restrict__ W2f,
    const u16* __restrict__ xT,
    const float* __restrict__ bb, const float* __restrict__ bc, const float* __restrict__ bd,
    const float* __restrict__ alpha, const float* __restrict__ beta,
    u16* __restrict__ yab, u16* __restrict__ ft)
{
    __shared__ u16 Wt[128][72];
    __shared__ u16 Xt[128][72];
    int t = threadIdx.x, lane = t & 63, w = t >> 6, q = lane >> 4, l15 = lane & 15;
    int nT_ = blockIdx.x, oT = blockIdx.y, batch = blockIdx.z;
    int n0 = nT_ * 128, o0 = oT * 128;
    const u16* Wsrc = (WHICH == 1 || oT == 0) ? (W1 + (size_t)o0 * CDIM)
                                              : (W2f + (size_t)(o0 - 128) * CDIM);
    const u16* xb = xT + ((size_t)batch * NT + n0) * CDIM;
    f32x4 acc[2][8];
    #pragma unroll
    for (int a = 0; a < 2; a++)
        #pragma unroll
        for (int b = 0; b < 8; b++) { f32x4 z = {0.f,0.f,0.f,0.f}; acc[a][b] = z; }

    for (int k0 = 0; k0 < CDIM; k0 += 64) {
        if (k0) __syncthreads();
        int r = t >> 1, h = t & 1;
        #pragma unroll
        for (int u = 0; u < 4; u++) {
            *(uint4*)&Wt[r][h * 32 + u * 8] = *(const uint4*)&Wsrc[(size_t)r * CDIM + k0 + h * 32 + u * 8];
            *(uint4*)&Xt[r][h * 32 + u * 8] = *(const uint4*)&xb[(size_t)r * CDIM + k0 + h * 32 + u * 8];
        }
        __syncthreads();
        if (oT == 0) {
            short8 af[2][2];
            #pragma unroll
            for (int ot = 0; ot < 2; ot++)
                #pragma unroll
                for (int kk = 0; kk < 2; kk++)
                    af[ot][kk] = *(const short8*)&Wt[w * 32 + ot * 16 + l15][kk * 32 + q * 8];
            #pragma unroll
            for (int kk = 0; kk < 2; kk++)
                #pragma unroll
                for (int i = 0; i < 8; i++) {
                    short8 bf = *(const short8*)&Xt[i * 16 + l15][kk * 32 + q * 8];
                    #pragma unroll
                    for (int ot = 0; ot < 2; ot++)
                        acc[ot][i] = __builtin_amdgcn_mfma_f32_16x16x32_bf16(af[ot][kk], bf, acc[ot][i], 0, 0, 0);
                }
        } else {
            short8 wf[2][2];
            #pragma unroll
            for (int ct = 0; ct < 2; ct++)
                #pragma unroll
                for (int kk = 0; kk < 2; kk++)
                    wf[ct][kk] = *(const short8*)&Wt[w * 32 + ct * 16 + l15][kk * 32 + q * 8];
            #pragma unroll
            for (int kk = 0; kk < 2; kk++)
                #pragma unroll
                for (int i = 0; i < 8; i++) {
                    short8 xf = *(const short8*)&Xt[i * 16 + l15][kk * 32 + q * 8];
                    #pragma unroll
                    for (int ct = 0; ct < 2; ct++)
                        acc[ct][i] = __builtin_amdgcn_mfma_f32_16x16x32_bf16(xf, wf[ct][kk], acc[ct][i], 0, 0, 0);
                }
        }
    }

    if (oT == 0) {
        #pragma unroll
        for (int ot = 0; ot < 2; ot++)
            #pragma unroll
            for (int i = 0; i < 8; i++) {
                int obase = w * 32 + ot * 16 + q * 4;
                int n = n0 + i * 16 + l15;
                U4 u;
                #pragma unroll
                for (int r = 0; r < 4; r++) {
                    int o = obase + r;
                    float bias = (o < 64) ? bb[o] * LOG2E : bc[o - 64];
                    u.v[r] = f2bf(acc[ot][i][r] + bias);
                }
                *(uint2*)&yab[((size_t)batch * NT + n) * 128 + obase] = u.u2;
            }
    } else {
        float bscale = (WHICH == 2) ? (alpha[0] + beta[0]) : 0.f;
        #pragma unroll
        for (int ct = 0; ct < 2; ct++)
            #pragma unroll
            for (int i = 0; i < 8; i++) {
                int c = (o0 - 128) + w * 32 + ct * 16 + l15;
                int mb = n0 + i * 16 + q * 4;
                u16* dst = &ft[((size_t)batch * CDIM + c) * NT + mb];
                U4 u;
                if (WHICH == 1) {
                    #pragma unroll
                    for (int r = 0; r < 4; r++) u.v[r] = f2bf(acc[ct][i][r]);
                } else {
                    U4 old; old.u2 = *(const uint2*)dst;
                    float bias = bd[c] * bscale;
                    #pragma unroll
                    for (int r = 0; r < 4; r++) u.v[r] = f2bf(acc[ct][i][r] + bf2f(old.v[r]) + bias);
                }
                *(uint2*)dst = u.u2;
            }
    }
}

// ---------------- denominators: denom[dir][b][n] = sum_m exp2(S - SHIFT) ----------------
__global__ __launch_bounds__(256, 4) void k_denom(
    const u16* __restrict__ yab1, const u16* __restrict__ yab2,
    float* __restrict__ denom)
{
    int t = threadIdx.x, lane = t & 63, w = t >> 6, q = lane >> 4, l15 = lane & 15;
    int x = blockIdx.x & 15;
    int batch = x & 1, m8 = x >> 1;
    int n0 = (blockIdx.x >> 4) * 32;
    const u16* y1 = yab1 + (size_t)batch * NT * 128;
    const u16* y2 = yab2 + (size_t)batch * NT * 128;

    short8 a1f[2][2], a2f[2][2];
    #pragma unroll
    for (int i = 0; i < 2; i++)
        #pragma unroll
        for (int kk = 0; kk < 2; kk++) {
            a1f[i][kk] = *(const short8*)&y1[(size_t)(n0 + i * 16 + l15) * 128 + kk * 32 + q * 8];
            a2f[i][kk] = *(const short8*)&y2[(size_t)(n0 + i * 16 + l15) * 128 + kk * 32 + q * 8];
        }

    float sm[2][2] = {{0.f,0.f},{0.f,0.f}};
    for (int mc = 0; mc < 512; mc += 64) {
        int mrow = m8 * 512 + mc + w * 16 + l15;
        const u16* r1 = y1 + (size_t)mrow * 128 + 64;
        const u16* r2 = y2 + (size_t)mrow * 128 + 64;
        short8 b1k0 = *(const short8*)(r1 + q * 8);
        short8 b1k1 = *(const short8*)(r1 + 32 + q * 8);
        short8 b2k0 = *(const short8*)(r2 + q * 8);
        short8 b2k1 = *(const short8*)(r2 + 32 + q * 8);
        #pragma unroll
        for (int i = 0; i < 2; i++) {
            f32x4 z = {0.f,0.f,0.f,0.f};
            f32x4 s12 = __builtin_amdgcn_mfma_f32_16x16x32_bf16(b2k0, a1f[i][0], z, 0, 0, 0);
            s12 = __builtin_amdgcn_mfma_f32_16x16x32_bf16(b2k1, a1f[i][1], s12, 0, 0, 0);
            f32x4 s21 = __builtin_amdgcn_mfma_f32_16x16x32_bf16(b1k0, a2f[i][0], z, 0, 0, 0);
            s21 = __builtin_amdgcn_mfma_f32_16x16x32_bf16(b1k1, a2f[i][1], s21, 0, 0, 0);
            #pragma unroll
            for (int r = 0; r < 4; r++) {
                sm[0][i] += fexp2(s12[r] - SHIFT);
                sm[1][i] += fexp2(s21[r] - SHIFT);
            }
        }
    }
    #pragma unroll
    for (int d = 0; d < 2; d++)
        #pragma unroll
        for (int i = 0; i < 2; i++) {
            float v = sm[d][i];
            v += __shfl_xor(v, 16);
            v += __shfl_xor(v, 32);
            if (q == 0)
                atomicAdd(&denom[((size_t)d * NB + batch) * NT + n0 + i * 16 + l15], v);
        }
}

// ---------------- P + apply: n-tile 32, m-split 2, XCD-clustered, pipelined ----------------
// xcd = blk&7 selects (batch, mh, n-low-bit) so each XCD works one 2MB ft-half (L2-resident).
__global__ __launch_bounds__(256, 2) void k_papply(
    const u16* __restrict__ yab1, const u16* __restrict__ yab2,
    const u16* __restrict__ ft, const float* __restrict__ denom,
    float* __restrict__ out, float* __restrict__ partial)
{
    __shared__ u16 b1t[128][72];
    __shared__ u16 b2t[128][72];
    __shared__ u16 Pt[32][136];
    int t = threadIdx.x, lane = t & 63, w = t >> 6, q = lane >> 4, l15 = lane & 15;
    int xcd = blockIdx.x & 7;
    int batch = xcd & 1, mh = (xcd >> 1) & 1, nbit = (xcd >> 2) & 1;
    int n0 = ((blockIdx.x >> 3) * 2 + nbit) * 32;
    const u16* y1 = yab1 + (size_t)batch * NT * 128;
    const u16* y2 = yab2 + (size_t)batch * NT * 128;
    const u16* ftb = ft + (size_t)batch * CDIM * NT;

    // loop-invariant a-fragments (B-operand: col=n, k=channel) from global
    short8 a1f[2][2], a2f[2][2];
    #pragma unroll
    for (int i = 0; i < 2; i++)
        #pragma unroll
        for (int kk = 0; kk < 2; kk++) {
            a1f[i][kk] = *(const short8*)&y1[(size_t)(n0 + i * 16 + l15) * 128 + kk * 32 + q * 8];
            a2f[i][kk] = *(const short8*)&y2[(size_t)(n0 + i * 16 + l15) * 128 + kk * 32 + q * 8];
        }
    float ls12[2], ls21[2];
    #pragma unroll
    for (int i = 0; i < 2; i++) {
        ls12[i] = SHIFT + flog2(denom[(size_t)batch * NT + n0 + i * 16 + l15]);
        ls21[i] = SHIFT + flog2(denom[((size_t)NB + batch) * NT + n0 + i * 16 + l15]);
    }

    f32x4 o[2][8];
    #pragma unroll
    for (int i = 0; i < 2; i++)
        #pragma unroll
        for (int j = 0; j < 8; j++) { f32x4 z = {0.f,0.f,0.f,0.f}; o[i][j] = z; }

    int sr = t >> 1, sh = t & 1;
    const int mbeg = mh * 2048, mend = mh * 2048 + 2048;
    // prologue: stage loads for first chunk
    uint4 sb1[4], sb2[4];
    #pragma unroll
    for (int u = 0; u < 4; u++) {
        sb1[u] = *(const uint4*)&y1[(size_t)(mbeg + sr) * 128 + 64 + sh * 32 + u * 8];
        sb2[u] = *(const uint4*)&y2[(size_t)(mbeg + sr) * 128 + 64 + sh * 32 + u * 8];
    }

    for (int mc = mbeg; mc < mend; mc += 128) {
        __syncthreads();                                   // (1) prev chunk done with b-tiles
        #pragma unroll
        for (int u = 0; u < 4; u++) {
            *(uint4*)&b1t[sr][sh * 32 + u * 8] = sb1[u];
            *(uint4*)&b2t[sr][sh * 32 + u * 8] = sb2[u];
        }
        __syncthreads();                                   // (2) b-tiles visible

        // issue next chunk's staging loads (consumed after next bar1 — a full phase of slack)
        if (mc + 128 < mend) {
            #pragma unroll
            for (int u = 0; u < 4; u++) {
                sb1[u] = *(const uint4*)&y1[(size_t)(mc + 128 + sr) * 128 + 64 + sh * 32 + u * 8];
                sb2[u] = *(const uint4*)&y2[(size_t)(mc + 128 + sr) * 128 + 64 + sh * 32 + u * 8];
            }
        }
        // preload first 4 c-tiles of ft for the apply phase (ready after bar3)
        short8 F[4][4];
        #pragma unroll
        for (int jj = 0; jj < 4; jj++) {
            const u16* fr = ftb + (size_t)(w * 128 + jj * 16 + l15) * NT + mc + q * 8;
            F[jj][0] = *(const short8*)(fr);
            F[jj][1] = *(const short8*)(fr + 32);
            F[jj][2] = *(const short8*)(fr + 64);
            F[jj][3] = *(const short8*)(fr + 96);
        }

        // ---- scores from LDS b-tiles ----
        #pragma unroll
        for (int mt = 0; mt < 2; mt++) {
            int ml = w * 32 + mt * 16 + l15;
            short8 bA1k0 = *(const short8*)&b1t[ml][q * 8];
            short8 bA1k1 = *(const short8*)&b1t[ml][32 + q * 8];
            short8 bA2k0 = *(const short8*)&b2t[ml][q * 8];
            short8 bA2k1 = *(const short8*)&b2t[ml][32 + q * 8];
            #pragma unroll
            for (int i = 0; i < 2; i++) {
                f32x4 z = {0.f,0.f,0.f,0.f};
                f32x4 s12 = __builtin_amdgcn_mfma_f32_16x16x32_bf16(bA2k0, a1f[i][0], z, 0, 0, 0);
                s12 = __builtin_amdgcn_mfma_f32_16x16x32_bf16(bA2k1, a1f[i][1], s12, 0, 0, 0);
                f32x4 s21 = __builtin_amdgcn_mfma_f32_16x16x32_bf16(bA1k0, a2f[i][0], z, 0, 0, 0);
                s21 = __builtin_amdgcn_mfma_f32_16x16x32_bf16(bA1k1, a2f[i][1], s21, 0, 0, 0);
                U4 u;
                #pragma unroll
                for (int r2 = 0; r2 < 4; r2++) {
                    float p12 = fexp2(s12[r2] - ls12[i]);
                    float p21 = fexp2(s21[r2] - ls21[i]);
                    u.v[r2] = f2bf(fabsf(p12 - p21));
                }
                *(uint2*)&Pt[i * 16 + l15][w * 32 + mt * 16 + q * 4] = u.u2;
            }
        }
        __syncthreads();                                   // (3) P visible
        short8 pa[2][4];
        #pragma unroll
        for (int i = 0; i < 2; i++)
            #pragma unroll
            for (int kk = 0; kk < 4; kk++)
                pa[i][kk] = *(const short8*)&Pt[i * 16 + l15][kk * 32 + q * 8];

        // ---- apply with 4-deep ft ring ----
        #pragma unroll
        for (int j = 0; j < 8; j++) {
            short8 fb0 = F[j & 3][0], fb1 = F[j & 3][1], fb2 = F[j & 3][2], fb3 = F[j & 3][3];
            if (j < 4) {
                const u16* fr = ftb + (size_t)(w * 128 + (j + 4) * 16 + l15) * NT + mc + q * 8;
                F[j][0] = *(const short8*)(fr);
                F[j][1] = *(const short8*)(fr + 32);
                F[j][2] = *(const short8*)(fr + 64);
                F[j][3] = *(const short8*)(fr + 96);
            }
            #pragma unroll
            for (int i = 0; i < 2; i++) {
                o[i][j] = __builtin_amdgcn_mfma_f32_16x16x32_bf16(pa[i][0], fb0, o[i][j], 0, 0, 0);
                o[i][j] = __builtin_amdgcn_mfma_f32_16x16x32_bf16(pa[i][1], fb1, o[i][j], 0, 0, 0);
                o[i][j] = __builtin_amdgcn_mfma_f32_16x16x32_bf16(pa[i][2], fb2, o[i][j], 0, 0, 0);
                o[i][j] = __builtin_amdgcn_mfma_f32_16x16x32_bf16(pa[i][3], fb3, o[i][j], 0, 0, 0);
            }
        }
    }

    float* dst = mh ? partial : out;
    #pragma unroll
    for (int i = 0; i < 2; i++)
        #pragma unroll
        for (int j = 0; j < 8; j++) {
            int c = w * 128 + j * 16 + l15;
            *(f32x4*)&dst[((size_t)batch * CDIM + c) * NT + n0 + i * 16 + q * 4] = o[i][j];
        }
}

// ---------------- out += partial ----------------
__global__ __launch_bounds__(256) void k_reduce(
    float* __restrict__ out, const float* __restrict__ part, int n4)
{
    int i = blockIdx.x * 256 + threadIdx.x, stride = gridDim.x * 256;
    float4* o4 = (float4*)out;
    const float4* p4 = (const float4*)part;
    for (int j = i; j < n4; j += stride) {
        float4 a = o4[j], b = p4[j];
        o4[j] = make_float4(a.x + b.x, a.y + b.y, a.z + b.z, a.w + b.w);
    }
}

extern "C" void kernel_launch(void* const* d_in, const int* in_sizes, int n_in,
                              void* d_out, int out_size, void* d_ws, size_t ws_size,
                              hipStream_t stream)
{
    const float* x1 = (const float*)d_in[0];
    const float* x2 = (const float*)d_in[1];
    const float* Wb = (const float*)d_in[2];
    const float* bb = (const float*)d_in[3];
    const float* Wc = (const float*)d_in[4];
    const float* bc = (const float*)d_in[5];
    const float* Wd = (const float*)d_in[6];
    const float* bd = (const float*)d_in[7];
    const float* alpha = (const float*)d_in[8];
    const float* beta  = (const float*)d_in[9];
    float* out = (float*)d_out;

    // ws layout (u16 units):
    u16* ws  = (u16*)d_ws;
    u16* x1T = ws;                      // [2][4096][512]  = 4,194,304
    u16* x2T = ws + 4194304;            //                 = 4,194,304
    u16* yab1 = ws + 8388608;           // [2][4096][128]  = 1,048,576
    u16* yab2 = ws + 9437184;           //                 = 1,048,576
    u16* ft   = ws + 10485760;          // [2][512][4096]  = 4,194,304
    u16* W1   = ws + 14680064;          // [640][512]      =   327,680
    u16* W2f  = ws + 15007744;          // [512][512]      =   262,144
    float* denom = (float*)(ws + 15269888);   // [2][2][4096] f32
    float* partial = (float*)ws;        // overlays x1T/x2T after GEMMs (16.8 MB)

    hipMemsetAsync(denom, 0, (size_t)2 * NB * NT * sizeof(float), stream);
    k_convW<<<1152, 256, 0, stream>>>(Wb, Wc, Wd, alpha, beta, W1, W2f);
    k_prep<<<dim3(8, 64, 4), 256, 0, stream>>>(x1, x2, x1T, x2T);
    k_gemm<1><<<dim3(32, 5, 2), 256, 0, stream>>>(W1, W2f, x1T, bb, bc, bd, alpha, beta, yab1, ft);
    k_gemm<2><<<dim3(32, 5, 2), 256, 0, stream>>>(W1, W2f, x2T, bb, bc, bd, alpha, beta, yab2, ft);
    k_denom<<<2048, 256, 0, stream>>>(yab1, yab2, denom);
    k_papply<<<512, 256, 0, stream>>>(yab1, yab2, ft, denom, out, partial);
    k_reduce<<<2048, 256, 0, stream>>>(out, partial, NB * CDIM * NT / 4);
}